// Round 2
// 306.521 us; speedup vs baseline: 1.3051x; 1.3051x over previous
//
#include <hip/hip_runtime.h>

// ---------------------------------------------------------------------------
// TraceSemanticHandshakeV342: fused concat+LayerNorm+Linear+GELU+Linear+GELU
// b=4, m=256, h=64, d=256, CAT=1283.  Rows = b*m*h = 65536.
// One block per (b,m): M=64 rows, N=256, K=1280 bf16 MFMA GEMM with LN folded
// into the epilogue.  All hot-path VMEM coalesced:
//  - weights K-blocked: w1L[kb][n][k%32] -> B-fragment loads contiguous 1KB/wave
//  - staging wave-per-row (lane l reads bytes l*16 of a 1KB row)
//  - T14: segment s+1 global loads issued before segment-s MFMA block
//  - y1 stored f32 XOR-swizzled; cvt to bf16 at GEMM2 read via v_cvt_pk_bf16_f32
// FIX vs prev round: prep_k store loop covered only n<64 (wrote 1/4 of the
// re-laid-out weights; rest was workspace garbage -> absmax 3.7).  Now loops
// gi=0..3 so all 256 n are written, still contiguous-1KB-per-wave stores.
// ---------------------------------------------------------------------------

typedef float  f32x4 __attribute__((ext_vector_type(4)));
typedef short  s16x8 __attribute__((ext_vector_type(8)));

__device__ __forceinline__ unsigned short f2bf(float f) {
    unsigned u = __builtin_bit_cast(unsigned, f);
    return (unsigned short)((u + 0x7fffu + ((u >> 16) & 1u)) >> 16);
}
__device__ __forceinline__ unsigned f2bf_pk(float lo, float hi) {
    unsigned ulo = __builtin_bit_cast(unsigned, lo);
    unsigned uhi = __builtin_bit_cast(unsigned, hi);
    ulo = (ulo + 0x7fffu + ((ulo >> 16) & 1u)) >> 16;
    uhi = (uhi + 0x7fffu + ((uhi >> 16) & 1u)) & 0xffff0000u;
    return ulo | uhi;
}
// tanh-form GELU: x*sigmoid(2*0.79788456*(x+0.044715 x^3)); max err ~4e-4.
__device__ __forceinline__ float gelu_t(float x) {
    float u2 = 1.5957691216057308f * x + 0.07135481627f * (x * x * x);
    float e  = __expf(u2);
    float r  = __builtin_amdgcn_rcpf(e + 1.0f);   // 1/(1+e^{2u}) ; e=inf -> 0
    return x - x * r;                              // x*sigmoid(2u)
}

// ---------------------------------------------------------------------------
// Prep: builds in d_ws
//   Sg[256], Sb[256] f32 (atomics over 40 k-blocks; ws pre-zeroed by memset)
//   w1L bf16, K-blocked: w1L[(kb*256+n)*32 + kl] = gamma[k]*W1[k][n],
//       k = kb*32+kl, kb in [0,40)
//   w2L bf16, K-blocked: w2L[(kb*256+n)*32 + kl] = W2[k][n], kb in [0,8)
// blocks 0..39: W1 (+ Sg/Sb partials); blocks 40..47: W2.
// ---------------------------------------------------------------------------
__global__ void __launch_bounds__(256)
prep_k(const float* __restrict__ W1, const float* __restrict__ W2,
       const float* __restrict__ gamma, const float* __restrict__ beta,
       float* __restrict__ Sg, float* __restrict__ Sb,
       short* __restrict__ w1t, short* __restrict__ w2t)
{
    __shared__ float tile[32][257];
    const int blk = blockIdx.x;
    const int t   = threadIdx.x;
    const int nl  = t >> 2, c = t & 3;    // per-wave: contiguous 1KB stores
    if (blk < 40) {
        float sg = 0.f, sb = 0.f;
#pragma unroll 4
        for (int kl = 0; kl < 32; ++kl) {
            int k = blk * 32 + kl;
            float w  = W1[k * 256 + t];       // coalesced 1KB row
            float gv = gamma[k];
            tile[kl][t] = gv * w;
            sg += gv * w;
            sb += beta[k] * w;
        }
        atomicAdd(&Sg[t], sg);
        atomicAdd(&Sb[t], sb);
        __syncthreads();
#pragma unroll
        for (int gi = 0; gi < 4; ++gi) {
            int n = gi * 64 + nl;
            uint4 o;
            o.x = f2bf_pk(tile[c*8+0][n], tile[c*8+1][n]);
            o.y = f2bf_pk(tile[c*8+2][n], tile[c*8+3][n]);
            o.z = f2bf_pk(tile[c*8+4][n], tile[c*8+5][n]);
            o.w = f2bf_pk(tile[c*8+6][n], tile[c*8+7][n]);
            *(uint4*)(w1t + (blk * 256 + n) * 32 + c * 8) = o;
        }
    } else {
        const int kb = blk - 40;
#pragma unroll 4
        for (int kl = 0; kl < 32; ++kl) {
            int k = kb * 32 + kl;
            tile[kl][t] = W2[k * 256 + t];
        }
        __syncthreads();
#pragma unroll
        for (int gi = 0; gi < 4; ++gi) {
            int n = gi * 64 + nl;
            uint4 o;
            o.x = f2bf_pk(tile[c*8+0][n], tile[c*8+1][n]);
            o.y = f2bf_pk(tile[c*8+2][n], tile[c*8+3][n]);
            o.z = f2bf_pk(tile[c*8+4][n], tile[c*8+5][n]);
            o.w = f2bf_pk(tile[c*8+6][n], tile[c*8+7][n]);
            *(uint4*)(w2t + (kb * 256 + n) * 32 + c * 8) = o;
        }
    }
}

// ---------------------------------------------------------------------------
// Main fused kernel. grid = 1024 (one per (b,m)); block = 256 (4 waves).
// Wave w owns columns [w*64, w*64+64) for GEMMs and rows [w*16,w*16+16) for
// staging/stats.
// LDS plan (66816 B total, 2 blocks/CU):
//   phase 1 (GEMM1):  As   bf16 A-tile [64 rows][32 x 16B-chunks, XOR-swz] @0 (32KB)
//                     pst  f32 stat partials [2][64 rows][64 lanes, swz]  @32KB (32KB)
//   phase 2 (GEMM2):  y1f  f32 [64][256] (chunk-of-4 XOR-swz)             @0 (64KB)
//   always:           mu/rs/t0/t1/t2 [64] each                            @64KB (1.25KB)
// ---------------------------------------------------------------------------
__global__ void __launch_bounds__(256, 2)
fused_main(const float* __restrict__ token, const float* __restrict__ step,
           const float* __restrict__ dyn,   const float* __restrict__ sem,
           const float* __restrict__ trace, const float* __restrict__ rel,
           const float* __restrict__ vis,   const float* __restrict__ gamma,
           const float* __restrict__ beta,  const float* __restrict__ W1,
           const float* __restrict__ b1v,   const float* __restrict__ b2v,
           const float* __restrict__ Sg,    const float* __restrict__ Sb,
           const short* __restrict__ w1t,   const short* __restrict__ w2t,
           float* __restrict__ out)
{
    __shared__ __align__(16) char lds_raw[66816];
    uint4* As                 = (uint4*)lds_raw;                 // 32 KB
    unsigned long long* As8   = (unsigned long long*)lds_raw;
    float* pst                = (float*)(lds_raw + 32768);       // 32 KB
    float* y1f                = (float*)lds_raw;                 // 64 KB (phase 2)
    float* mu_s               = (float*)(lds_raw + 65536);
    float* rs_s               = mu_s + 64;
    float* t0s                = mu_s + 128;
    float* t1s                = mu_s + 192;
    float* t2s                = mu_s + 256;

    const int t    = threadIdx.x;
    const int bm   = blockIdx.x;          // b*256 + m
    const int b_i  = bm >> 8;
    const int lane = t & 63;
    const int wv   = t >> 6;
    const int l15  = lane & 15;
    const int q    = lane >> 4;
    const int n0   = wv * 64;             // GEMM column base
    const int r0   = wv * 16;             // staging row base

    const float* base0 = token + bm * 256;                  // stride 0 (broadcast)
    const float* base1 = step  + (b_i * 64 + r0) * 256;
    const float* base2 = dyn   + (bm * 64 + r0) * 256;
    const float* base3 = sem   + (bm * 64 + r0) * 256;
    const float* base4 = trace + (bm * 64 + r0) * 256;

    f32x4 acc[4][4];
    float s1[16], s2[16];
#pragma unroll
    for (int i = 0; i < 4; ++i)
#pragma unroll
        for (int j = 0; j < 4; ++j)
            acc[i][j] = (f32x4){0.f, 0.f, 0.f, 0.f};
#pragma unroll
    for (int j = 0; j < 16; ++j) { s1[j] = 0.f; s2[j] = 0.f; }

    float4 g[16];

    // Coalesced wave-per-row load: lane l reads bytes [l*16, l*16+16) of row j.
#define LOAD_SEG(BASE, STRIDE)                                                 \
    _Pragma("unroll")                                                          \
    for (int j = 0; j < 16; ++j)                                               \
        g[j] = *((const float4*)((BASE) + j * (STRIDE)) + lane);

    // Consume g: accumulate per-lane LN partials, pack to bf16, write As with
    // 16B-chunk XOR swizzle (chunk c = lane>>1, half = lane&1; c ^= row&7).
#define STATS_CVT_WRITE()                                                      \
    _Pragma("unroll")                                                          \
    for (int j = 0; j < 16; ++j) {                                             \
        float4 v = g[j];                                                       \
        s1[j] += v.x + v.y + v.z + v.w;                                        \
        s2[j] += v.x*v.x + v.y*v.y + v.z*v.z + v.w*v.w;                        \
        int m_ = r0 + j;                                                       \
        unsigned long long pk_ = (unsigned long long)f2bf_pk(v.x, v.y)         \
                               | ((unsigned long long)f2bf_pk(v.z, v.w) << 32);\
        As8[(m_ * 32 + ((lane >> 1) ^ (j & 7))) * 2 + (lane & 1)] = pk_;       \
    }

    // B loads coalesced: per (kc,nt) the wave reads a contiguous 1KB of
    // w1L[kb = SEG*8+kc][n0+nt*16 .. +16][0..32).
#define MFMA_SEG(SEG)                                                          \
    _Pragma("unroll")                                                          \
    for (int kc = 0; kc < 8; ++kc) {                                           \
        const short* wk_ = w1t + ((SEG) * 8 + kc) * 8192;                      \
        s16x8 bfr[4];                                                          \
        _Pragma("unroll")                                                      \
        for (int nt = 0; nt < 4; ++nt)                                         \
            bfr[nt] = *(const s16x8*)(wk_ + (n0 + nt * 16 + l15) * 32 + q * 8);\
        s16x8 afr[4];                                                          \
        _Pragma("unroll")                                                      \
        for (int mt = 0; mt < 4; ++mt) {                                       \
            int m_ = mt * 16 + l15;                                            \
            afr[mt] = *(const s16x8*)&As[m_ * 32 + ((kc * 4 + q) ^ (m_ & 7))]; \
        }                                                                      \
        _Pragma("unroll")                                                      \
        for (int mt = 0; mt < 4; ++mt)                                         \
            _Pragma("unroll")                                                  \
            for (int nt = 0; nt < 4; ++nt)                                     \
                acc[mt][nt] = __builtin_amdgcn_mfma_f32_16x16x32_bf16(         \
                    afr[mt], bfr[nt], acc[mt][nt], 0, 0, 0);                   \
    }

    // ---- software-pipelined GEMM1: load(s+1) issued before MFMA(s) --------
    LOAD_SEG(base0, 0);            // token broadcast (CSEs to one load)
    STATS_CVT_WRITE();
    __syncthreads();
    LOAD_SEG(base1, 256);
    MFMA_SEG(0);
    __syncthreads();
    STATS_CVT_WRITE();
    __syncthreads();
    LOAD_SEG(base2, 256);
    MFMA_SEG(1);
    __syncthreads();
    STATS_CVT_WRITE();
    __syncthreads();
    LOAD_SEG(base3, 256);
    MFMA_SEG(2);
    __syncthreads();
    STATS_CVT_WRITE();
    __syncthreads();
    LOAD_SEG(base4, 256);
    MFMA_SEG(3);
    __syncthreads();
    STATS_CVT_WRITE();
    __syncthreads();
    MFMA_SEG(4);

    // ---- LN stats: per-lane partials -> pst -> one-wave reduce ------------
    // write: lane l, row r: f32 index ((l>>2)^(r&7))*4 + (l&3) within row.
#pragma unroll
    for (int j = 0; j < 16; ++j) {
        int r  = r0 + j;
        int ci = (((lane >> 2) ^ (j & 7)) << 2) + (lane & 3);
        pst[r * 64 + ci]        = s1[j];
        pst[4096 + r * 64 + ci] = s2[j];
    }
    __syncthreads();

    if (t < 64) {
        const int r = t;
        float S1 = 0.f, S2 = 0.f;
#pragma unroll
        for (int i = 0; i < 16; ++i) {
            int c = i ^ (r & 7);
            const f32x4 a = *(const f32x4*)&pst[r * 64 + (c << 2)];
            const f32x4 b = *(const f32x4*)&pst[4096 + r * 64 + (c << 2)];
            S1 += a[0] + a[1] + a[2] + a[3];
            S2 += b[0] + b[1] + b[2] + b[3];
        }
        float x0 = rel[(bm * 64 + r) * 2 + 0];
        float x1 = rel[(bm * 64 + r) * 2 + 1];
        float x2 = vis[bm * 64 + r];
        S1 += x0 + x1 + x2;
        S2 += x0 * x0 + x1 * x1 + x2 * x2;
        const float inv = 1.0f / 1283.0f;
        float mu  = S1 * inv;
        float var = S2 * inv - mu * mu;
        float rs  = rsqrtf(var + 1e-5f);
        mu_s[r] = mu;
        rs_s[r] = rs;
        t0s[r] = (x0 - mu) * rs * gamma[1280] + beta[1280];
        t1s[r] = (x1 - mu) * rs * gamma[1281] + beta[1281];
        t2s[r] = (x2 - mu) * rs * gamma[1282] + beta[1282];
    }
    __syncthreads();

    // ---- epilogue 1: LN fixup + tail + bias + GELU -> y1 f32 (swizzled) ---
#pragma unroll
    for (int nt = 0; nt < 4; ++nt) {
        int n = n0 + nt * 16 + l15;
        float sg  = Sg[n], sb = Sb[n], bb = b1v[n];
        float wt0 = W1[1280 * 256 + n];
        float wt1 = W1[1281 * 256 + n];
        float wt2 = W1[1282 * 256 + n];
#pragma unroll
        for (int mt = 0; mt < 4; ++mt) {
#pragma unroll
            for (int r4 = 0; r4 < 4; ++r4) {
                int r = mt * 16 + q * 4 + r4;
                float rsv = rs_s[r], muv = mu_s[r];
                float v = rsv * acc[mt][nt][r4] - rsv * muv * sg + sb + bb
                        + t0s[r] * wt0 + t1s[r] * wt1 + t2s[r] * wt2;
                v = gelu_t(v);
                y1f[r * 256 + ((((n >> 2) ^ (r & 7)) << 2) | (n & 3))] = v;
            }
        }
    }
    __syncthreads();

    // ---- GEMM2: y1 (f32 in LDS, cvt at read) @ w2L (coalesced global) -----
    f32x4 acc2[4][4];
#pragma unroll
    for (int i = 0; i < 4; ++i)
#pragma unroll
        for (int j = 0; j < 4; ++j)
            acc2[i][j] = (f32x4){0.f, 0.f, 0.f, 0.f};

#pragma unroll
    for (int kc = 0; kc < 8; ++kc) {
        const short* wk = w2t + kc * 8192;
        s16x8 bfr[4];
#pragma unroll
        for (int nt = 0; nt < 4; ++nt)
            bfr[nt] = *(const s16x8*)(wk + (n0 + nt * 16 + l15) * 32 + q * 8);
        s16x8 afr[4];
#pragma unroll
        for (int mt = 0; mt < 4; ++mt) {
            int m  = mt * 16 + l15;
            int s  = m & 7;
            int c0 = kc * 8 + q * 2;   // even 4-f32-chunk index
            const f32x4 lo = *(const f32x4*)&y1f[m * 256 + ((c0 ^ s) << 2)];
            const f32x4 hi = *(const f32x4*)&y1f[m * 256 + (((c0 + 1) ^ s) << 2)];
            unsigned p0, p1, p2, p3;
            asm("v_cvt_pk_bf16_f32 %0, %1, %2" : "=v"(p0) : "v"(lo[0]), "v"(lo[1]));
            asm("v_cvt_pk_bf16_f32 %0, %1, %2" : "=v"(p1) : "v"(lo[2]), "v"(lo[3]));
            asm("v_cvt_pk_bf16_f32 %0, %1, %2" : "=v"(p2) : "v"(hi[0]), "v"(hi[1]));
            asm("v_cvt_pk_bf16_f32 %0, %1, %2" : "=v"(p3) : "v"(hi[2]), "v"(hi[3]));
            uint4 u;
            u.x = p0; u.y = p1; u.z = p2; u.w = p3;
            afr[mt] = __builtin_bit_cast(s16x8, u);
        }
#pragma unroll
        for (int mt = 0; mt < 4; ++mt)
#pragma unroll
            for (int nt = 0; nt < 4; ++nt)
                acc2[mt][nt] = __builtin_amdgcn_mfma_f32_16x16x32_bf16(
                    afr[mt], bfr[nt], acc2[mt][nt], 0, 0, 0);
    }

    // ---- epilogue 2: + b2, GELU, store f32 (line-minimal already) ---------
#pragma unroll
    for (int nt = 0; nt < 4; ++nt) {
        int n = n0 + nt * 16 + l15;
        float bb = b2v[n];
#pragma unroll
        for (int mt = 0; mt < 4; ++mt)
#pragma unroll
            for (int r4 = 0; r4 < 4; ++r4) {
                int r = mt * 16 + q * 4 + r4;
                out[(bm * 64 + r) * 256 + n] = gelu_t(acc2[mt][nt][r4] + bb);
            }
    }
#undef LOAD_SEG
#undef STATS_CVT_WRITE
#undef MFMA_SEG
}

// ---------------------------------------------------------------------------
extern "C" void kernel_launch(void* const* d_in, const int* in_sizes, int n_in,
                              void* d_out, int out_size, void* d_ws, size_t ws_size,
                              hipStream_t stream) {
    const float* token = (const float*)d_in[0];
    const float* step  = (const float*)d_in[1];
    const float* dyn   = (const float*)d_in[2];
    const float* sem   = (const float*)d_in[3];
    const float* trace = (const float*)d_in[4];
    const float* rel   = (const float*)d_in[5];
    const float* vis   = (const float*)d_in[6];
    const float* gamma = (const float*)d_in[7];
    const float* beta  = (const float*)d_in[8];
    const float* W1    = (const float*)d_in[9];
    const float* b1    = (const float*)d_in[10];
    const float* W2    = (const float*)d_in[11];
    const float* b2    = (const float*)d_in[12];

    // ws layout: [0,1KB) Sg f32, [1KB,2KB) Sb f32, then w1L bf16 (655360 B),
    // then w2L bf16 (131072 B).  Total 788480 B.
    float* Sg  = (float*)d_ws;
    float* Sb  = Sg + 256;
    short* w1t = (short*)((char*)d_ws + 2048);
    short* w2t = w1t + 1280 * 256;
    float* out = (float*)d_out;

    hipMemsetAsync(d_ws, 0, 2048, stream);
    hipLaunchKernelGGL(prep_k, dim3(48), dim3(256), 0, stream,
                       W1, W2, gamma, beta, Sg, Sb, w1t, w2t);
    hipLaunchKernelGGL(fused_main, dim3(1024), dim3(256), 0, stream,
                       token, step, dyn, sem, trace, rel, vis, gamma, beta,
                       W1, b1, b2, Sg, Sb, w1t, w2t, out);
}